// Round 9
// baseline (2622.290 us; speedup 1.0000x reference)
//
#include <hip/hip_runtime.h>

#define HWC 36864
#define HW2 18432
#define WID 192
#define LOG2E 1.4426950408889634f

typedef float f2 __attribute__((ext_vector_type(2)));

__device__ __forceinline__ float gelu_exact(float v) {
  return 0.5f * v * (1.0f + erff(v * 0.70710678118654752f));
}

// ---- weight transpose: (Cout,Cin) -> (Cin,Cout) ----
__global__ __launch_bounds__(256) void wtr_k(const float* __restrict__ w, float* __restrict__ o,
                                             int Cout, int Cin) {
  int i = blockIdx.x * 256 + threadIdx.x;
  if (i < Cout * Cin) { int co = i / Cin, ci = i - co * Cin; o[ci * Cout + co] = w[i]; }
}

// ---- weight transpose with LN-gamma fold: wt[ci][co] = w[co][ci]*lnw[ci] ----
__global__ __launch_bounds__(256) void prepfold_k(const float* __restrict__ w, const float* __restrict__ lnw,
                                                  float* __restrict__ o, int Cout, int Cin) {
  int i = blockIdx.x * 256 + threadIdx.x;
  if (i < Cout * Cin) { int co = i / Cin, ci = i - co * Cin; o[ci * Cout + co] = w[i] * lnw[ci]; }
}

// ---- per-co reductions for the LN fold ----
__global__ __launch_bounds__(256) void rowsum_k(const float* __restrict__ wt_t, const float* __restrict__ w_orig,
                                                const float* __restrict__ lnb, const float* __restrict__ bias,
                                                float* __restrict__ S, float* __restrict__ Kb,
                                                int Cout, int Cin) {
  int co = blockIdx.x * 256 + threadIdx.x;
  if (co >= Cout) return;
  float s = 0.f, kb = 0.f;
  for (int ci = 0; ci < Cin; ++ci) {
    s += wt_t[ci * Cout + co];
    kb = fmaf(w_orig[co * Cin + ci], lnb[ci], kb);
  }
  S[co] = s;
  Kb[co] = kb + bias[co];
}

// ---- conv-conv fusion: wt[ci][co] = sum_k w2[co][k]*w1[k][ci]; Kb[co] = b2[co] + sum_k w2[co][k]*b1[k] ----
__global__ __launch_bounds__(256) void wprod_k(const float* __restrict__ w2, const float* __restrict__ w1,
                                               const float* __restrict__ b1, const float* __restrict__ b2,
                                               float* __restrict__ wt, float* __restrict__ Kb,
                                               int Cout, int Cmid, int Cin) {
  int i = blockIdx.x * 256 + threadIdx.x;
  if (i >= Cout * Cin) return;
  int co = i / Cin, ci = i - co * Cin;
  float s = 0.f;
  for (int k = 0; k < Cmid; ++k)
    s = fmaf(w2[co * Cmid + k], w1[k * Cin + ci], s);
  wt[ci * Cout + co] = s;
  if (ci == 0) {
    float kb = 0.f;
    for (int k = 0; k < Cmid; ++k) kb = fmaf(w2[co * Cmid + k], b1[k], kb);
    Kb[co] = kb + b2[co];
  }
}

// ---- per-pixel LN stats over C=128 for ONE batch image: musig[p] = {mu0, rs0, mu1, rs1} ----
__global__ __launch_bounds__(256) void stat_k(const f2* __restrict__ x, float4* __restrict__ musig) {
  int p = blockIdx.x * 256 + threadIdx.x;        // 0 .. HW2-1
  f2 s = {0.f, 0.f}, q = {0.f, 0.f};
  for (int c = 0; c < 128; ++c) {
    f2 v = x[p + (long)c * HW2];
    s += v;
    q = __builtin_elementwise_fma(v, v, q);
  }
  f2 mu = s * (1.0f / 128.0f);
  f2 var = q * (1.0f / 128.0f) - mu * mu;
  musig[p] = make_float4(mu.x, rsqrtf(var.x + 1e-5f), mu.y, rsqrtf(var.y + 1e-5f));
}

// ---- conv1x1 as GEMM for ONE batch image, f2-packed (2 pixels/thread) ----
template<int CIN, int COUT, int TILE, bool RESID, bool FOLD>
__global__ __launch_bounds__(256) void conv1x1_k(const f2* __restrict__ in, const float* __restrict__ wt,
                                                 const float* __restrict__ bias, const f2* __restrict__ resid,
                                                 f2* __restrict__ out,
                                                 const float4* __restrict__ musig, const float* __restrict__ S) {
  int p = blockIdx.x * 256 + threadIdx.x;    // 0 .. HW2-1
  int co0 = blockIdx.y * TILE;
  const f2* ip = in + p;
  const float* wp = wt + co0;
  f2 acc[TILE];
  #pragma unroll
  for (int i = 0; i < TILE; ++i) acc[i] = (f2){0.f, 0.f};
  for (int ci = 0; ci < CIN; ++ci) {
    f2 v = ip[(long)ci * HW2];
    #pragma unroll
    for (int co = 0; co < TILE; ++co) {
      float w = wp[ci * COUT + co];
      acc[co] = __builtin_elementwise_fma(v, (f2){w, w}, acc[co]);
    }
  }
  float4 ms;
  if (FOLD) ms = musig[p];
  #pragma unroll
  for (int co = 0; co < TILE; ++co) {
    f2 r;
    if (FOLD) {
      float sc = S[co0 + co], kb = bias[co0 + co];
      r.x = fmaf(ms.y, acc[co].x - ms.x * sc, kb);
      r.y = fmaf(ms.w, acc[co].y - ms.z * sc, kb);
    } else {
      float bc = bias[co0 + co];
      r = acc[co] + (f2){bc, bc};
    }
    if (RESID) r += resid[(long)(co0 + co) * HW2 + p];
    out[(long)(co0 + co) * HW2 + p] = r;
  }
}

// ---- fused depthwise 3x3 -> depthwise 3x3 for ONE batch image (zero-pad exact) ----
template<bool TR, bool TROUT>
__global__ __launch_bounds__(256) void dwdw_k(const float* __restrict__ in,
                                              const float* __restrict__ w2, const float* __restrict__ b2,
                                              const float* __restrict__ w3, const float* __restrict__ b3,
                                              float* __restrict__ out) {
  __shared__ float sIn[36 * 36];
  __shared__ float sMid[34 * 34];
  __shared__ float sOut[32 * 33];
  int tid = threadIdx.x;
  int tb = blockIdx.x;                 // 0..35 (6x6 tiles of 32x32)
  int c = blockIdx.y;                  // channel/plane
  int h0 = (tb / 6) * 32, w0 = (tb % 6) * 32;
  const float* ip = in + (long)c * HWC;
  float k2[9], k3[9];
  #pragma unroll
  for (int i = 0; i < 3; ++i)
    #pragma unroll
    for (int j = 0; j < 3; ++j) {
      k2[i * 3 + j] = w2[c * 9 + (TR ? j * 3 + i : i * 3 + j)];
      k3[i * 3 + j] = w3[c * 9 + (TR ? j * 3 + i : i * 3 + j)];
    }
  float bb2 = b2[c], bb3 = b3[c];
  for (int t = tid; t < 36 * 36; t += 256) {
    int i = t / 36, j = t - i * 36;
    int h = h0 - 2 + i, w = w0 - 2 + j;
    sIn[t] = (h >= 0 && h < WID && w >= 0 && w < WID) ? ip[h * WID + w] : 0.f;
  }
  __syncthreads();
  for (int t = tid; t < 34 * 34; t += 256) {
    int i = t / 34, j = t - i * 34;
    int h = h0 - 1 + i, w = w0 - 1 + j;
    float acc = 0.f;
    if (h >= 0 && h < WID && w >= 0 && w < WID) {
      acc = bb2;
      #pragma unroll
      for (int di = 0; di < 3; ++di)
        #pragma unroll
        for (int dj = 0; dj < 3; ++dj)
          acc = fmaf(k2[di * 3 + dj], sIn[(i + di) * 36 + j + dj], acc);
    }
    sMid[t] = acc;
  }
  __syncthreads();
  #pragma unroll
  for (int tt = 0; tt < 4; ++tt) {
    int t = tid + tt * 256;
    int i = t >> 5, j = t & 31;
    float acc = bb3;
    #pragma unroll
    for (int di = 0; di < 3; ++di)
      #pragma unroll
      for (int dj = 0; dj < 3; ++dj)
        acc = fmaf(k3[di * 3 + dj], sMid[(i + di) * 34 + j + dj], acc);
    if (TROUT) sOut[i * 33 + j] = acc;
    else       out[(long)c * HWC + (h0 + i) * WID + w0 + j] = acc;
  }
  if (TROUT) {
    __syncthreads();
    #pragma unroll
    for (int tt = 0; tt < 4; ++tt) {
      int t = tid + tt * 256;
      int a = t >> 5, b = t & 31;
      out[(long)c * HWC + (w0 + a) * WID + h0 + b] = sOut[b * 33 + a];
    }
  }
}

// ---- fused depthwise 3x3 (680ch) + cross-GELU gate -> 340ch, ONE batch image ----
__global__ __launch_bounds__(256) void dw3gate_k(const float* __restrict__ in, const float* __restrict__ wk,
                                                 const float* __restrict__ bias, float* __restrict__ g) {
  int idx = blockIdx.x * 256 + threadIdx.x;      // < 340*HWC
  int w = idx % WID;
  int t = idx / WID;
  int h = t % WID;
  int c = t / WID;            // 0..339
  const float* ip1 = in + (long)c * HWC;
  const float* ip2 = ip1 + (long)340 * HWC;
  float a = bias[c], bb = bias[c + 340];
  #pragma unroll
  for (int i = 0; i < 3; ++i) {
    int hh = h + i - 1;
    if (hh < 0 || hh >= WID) continue;
    #pragma unroll
    for (int j = 0; j < 3; ++j) {
      int ww = w + j - 1;
      if (ww < 0 || ww >= WID) continue;
      int off = hh * WID + ww;
      a  = fmaf(wk[c * 9 + i * 3 + j],         ip1[off], a);
      bb = fmaf(wk[(c + 340) * 9 + i * 3 + j], ip2[off], bb);
    }
  }
  g[(long)c * HWC + h * WID + w] = gelu_exact(bb) * a + gelu_exact(a) * bb;
}

// ---- h<->w transpose of one (192,192) plane per blockIdx.y ----
__global__ __launch_bounds__(256) void thw_k(const float* __restrict__ in, float* __restrict__ out) {
  __shared__ float tile[32][33];
  int tb = blockIdx.x;         // 0..35
  int h0 = (tb / 6) * 32, w0 = (tb % 6) * 32;
  long base = (long)blockIdx.y * HWC;
  int tx = threadIdx.x & 31, ty = threadIdx.x >> 5;
  #pragma unroll
  for (int k = 0; k < 4; ++k)
    tile[ty + 8 * k][tx] = in[base + (h0 + ty + 8 * k) * WID + w0 + tx];
  __syncthreads();
  #pragma unroll
  for (int k = 0; k < 4; ++k)
    out[base + (w0 + ty + 8 * k) * WID + h0 + tx] = tile[tx][ty + 8 * k];
}

// ---- repack K,V rows of one batch's qkv into kv[g*192+r][j][64] (K d=0..31, V d=32..63) ----
__global__ __launch_bounds__(384) void rpk_k(const float* __restrict__ qkv, float* __restrict__ kv) {
  __shared__ float T[64 * 193];
  int bid = blockIdx.x;            // g*192 + r
  int r = bid % WID;
  int g = bid / WID;               // 0..3
  int t = threadIdx.x;
  for (int e = t; e < 64 * 192; e += 384) {
    int ch = e / 192, j = e - ch * 192;      // coalesced read along j
    int which = ch >> 5, d = ch & 31;
    long plane = 128 + which * 128 + g * 32 + d;
    T[ch * 193 + j] = qkv[plane * HWC + (long)r * WID + j];
  }
  __syncthreads();
  long ob = (long)bid * (192 * 64);
  for (int e = t; e < 64 * 192; e += 384) {
    int j = e >> 6, c = e & 63;              // coalesced write
    kv[ob + e] = T[c * 193 + j];
  }
}

// ---- axial attention (one batch image): one block (384 thr) per (g, row) ----
// 2-way key split (s = tid/192 handles keys [96s, 96s+96)); partials merged via LDS.
// Exact: softmax shift is the fixed constant |f| (|q.k|<=1), so partial sums are additive.
// Per-j loads are DOUBLE-BUFFERED in statically-named registers (A/B) so all 16 b128 of
// row j+1 are in flight while row j computes; __launch_bounds__(384,1) lifts the VGPR cap
// (r8 post-mortem: at 68 VGPR the compiler serialized loads -> 5270 cyc/j latency chain).
#define LOADKV(P, jj) { const float4* _kj = (const float4*)(rowp + (jj) * 64); \
    P##k0 = _kj[0];  P##k1 = _kj[1];  P##k2 = _kj[2];  P##k3 = _kj[3];  \
    P##k4 = _kj[4];  P##k5 = _kj[5];  P##k6 = _kj[6];  P##k7 = _kj[7];  \
    P##v0 = _kj[8];  P##v1 = _kj[9];  P##v2 = _kj[10]; P##v3 = _kj[11]; \
    P##v4 = _kj[12]; P##v5 = _kj[13]; P##v6 = _kj[14]; P##v7 = _kj[15]; }

#define COMPUTEKV(P) { \
    f2 a0 = {0.f,0.f}, a1 = {0.f,0.f}, a2 = {0.f,0.f}, a3 = {0.f,0.f}; \
    a0 = __builtin_elementwise_fma(qr2[0],  (f2){P##k0.x, P##k0.y}, a0); \
    a1 = __builtin_elementwise_fma(qr2[1],  (f2){P##k0.z, P##k0.w}, a1); \
    a2 = __builtin_elementwise_fma(qr2[2],  (f2){P##k1.x, P##k1.y}, a2); \
    a3 = __builtin_elementwise_fma(qr2[3],  (f2){P##k1.z, P##k1.w}, a3); \
    a0 = __builtin_elementwise_fma(qr2[4],  (f2){P##k2.x, P##k2.y}, a0); \
    a1 = __builtin_elementwise_fma(qr2[5],  (f2){P##k2.z, P##k2.w}, a1); \
    a2 = __builtin_elementwise_fma(qr2[6],  (f2){P##k3.x, P##k3.y}, a2); \
    a3 = __builtin_elementwise_fma(qr2[7],  (f2){P##k3.z, P##k3.w}, a3); \
    a0 = __builtin_elementwise_fma(qr2[8],  (f2){P##k4.x, P##k4.y}, a0); \
    a1 = __builtin_elementwise_fma(qr2[9],  (f2){P##k4.z, P##k4.w}, a1); \
    a2 = __builtin_elementwise_fma(qr2[10], (f2){P##k5.x, P##k5.y}, a2); \
    a3 = __builtin_elementwise_fma(qr2[11], (f2){P##k5.z, P##k5.w}, a3); \
    a0 = __builtin_elementwise_fma(qr2[12], (f2){P##k6.x, P##k6.y}, a0); \
    a1 = __builtin_elementwise_fma(qr2[13], (f2){P##k6.z, P##k6.w}, a1); \
    a2 = __builtin_elementwise_fma(qr2[14], (f2){P##k7.x, P##k7.y}, a2); \
    a3 = __builtin_elementwise_fma(qr2[15], (f2){P##k7.z, P##k7.w}, a3); \
    f2 asum = (a0 + a1) + (a2 + a3); \
    float p = exp2f(fmaf(asum.x + asum.y, fl2, -ml2)); \
    lsum += p; \
    f2 ps = {p, p}; \
    o2[0]  = __builtin_elementwise_fma(ps, (f2){P##v0.x, P##v0.y}, o2[0]);  \
    o2[1]  = __builtin_elementwise_fma(ps, (f2){P##v0.z, P##v0.w}, o2[1]);  \
    o2[2]  = __builtin_elementwise_fma(ps, (f2){P##v1.x, P##v1.y}, o2[2]);  \
    o2[3]  = __builtin_elementwise_fma(ps, (f2){P##v1.z, P##v1.w}, o2[3]);  \
    o2[4]  = __builtin_elementwise_fma(ps, (f2){P##v2.x, P##v2.y}, o2[4]);  \
    o2[5]  = __builtin_elementwise_fma(ps, (f2){P##v2.z, P##v2.w}, o2[5]);  \
    o2[6]  = __builtin_elementwise_fma(ps, (f2){P##v3.x, P##v3.y}, o2[6]);  \
    o2[7]  = __builtin_elementwise_fma(ps, (f2){P##v3.z, P##v3.w}, o2[7]);  \
    o2[8]  = __builtin_elementwise_fma(ps, (f2){P##v4.x, P##v4.y}, o2[8]);  \
    o2[9]  = __builtin_elementwise_fma(ps, (f2){P##v4.z, P##v4.w}, o2[9]);  \
    o2[10] = __builtin_elementwise_fma(ps, (f2){P##v5.x, P##v5.y}, o2[10]); \
    o2[11] = __builtin_elementwise_fma(ps, (f2){P##v5.z, P##v5.w}, o2[11]); \
    o2[12] = __builtin_elementwise_fma(ps, (f2){P##v6.x, P##v6.y}, o2[12]); \
    o2[13] = __builtin_elementwise_fma(ps, (f2){P##v6.z, P##v6.w}, o2[13]); \
    o2[14] = __builtin_elementwise_fma(ps, (f2){P##v7.x, P##v7.y}, o2[14]); \
    o2[15] = __builtin_elementwise_fma(ps, (f2){P##v7.z, P##v7.w}, o2[15]); }

__global__ __launch_bounds__(384, 1) void attn_k(const float* __restrict__ qkv,
                                                 const float* __restrict__ kv,
                                                 float* __restrict__ outp,
                                                 const float* __restrict__ factor) {
  __shared__ float M[192 * 33];    // stride 33: conflict-free partial-merge buffer
  int tid = threadIdx.x;
  int s = tid >= 192 ? 1 : 0;
  int l = tid - s * 192;
  int bid = blockIdx.x;
  int r = bid % WID;
  int g = bid / WID;
  long bq = (long)(g * 32) * HWC + (long)r * WID;
  // Q -> registers, l2-normalize
  f2 qr2[16]; float qn = 0.f;
  #pragma unroll
  for (int d = 0; d < 16; ++d) {
    f2 a = { qkv[bq + (long)(2 * d) * HWC + l], qkv[bq + (long)(2 * d + 1) * HWC + l] };
    qr2[d] = a;
    qn += a.x * a.x + a.y * a.y;
  }
  float qs = 1.0f / fmaxf(sqrtf(qn), 1e-12f);
  #pragma unroll
  for (int d = 0; d < 16; ++d) qr2[d] *= qs;

  const float* rowp = kv + (long)bid * (192 * 64) + (long)s * (96 * 64);
  float f = factor[0];
  float fl2 = f * LOG2E, ml2 = fabsf(f) * LOG2E;   // |q.k|<=1 -> exact shift, no max pass
  f2 o2[16];
  #pragma unroll
  for (int d = 0; d < 16; ++d) o2[d] = (f2){0.f, 0.f};
  float lsum = 0.f;
  float4 Ak0, Ak1, Ak2, Ak3, Ak4, Ak5, Ak6, Ak7, Av0, Av1, Av2, Av3, Av4, Av5, Av6, Av7;
  float4 Bk0, Bk1, Bk2, Bk3, Bk4, Bk5, Bk6, Bk7, Bv0, Bv1, Bv2, Bv3, Bv4, Bv5, Bv6, Bv7;
  LOADKV(A, 0)
  for (int j = 0; j < 96; j += 2) {
    LOADKV(B, j + 1)
    COMPUTEKV(A)
    if (j + 2 < 96) LOADKV(A, j + 2)
    COMPUTEKV(B)
  }
  // merge the two key-halves via LDS
  if (s == 1) {
    #pragma unroll
    for (int d = 0; d < 16; ++d) {
      M[l * 33 + 2 * d]     = o2[d].x;
      M[l * 33 + 2 * d + 1] = o2[d].y;
    }
    M[l * 33 + 32] = lsum;
  }
  __syncthreads();
  if (s == 0) {
    #pragma unroll
    for (int d = 0; d < 16; ++d) {
      o2[d].x += M[l * 33 + 2 * d];
      o2[d].y += M[l * 33 + 2 * d + 1];
    }
    lsum += M[l * 33 + 32];
    float inv = 1.0f / lsum;
    #pragma unroll
    for (int d = 0; d < 16; ++d) {
      outp[bq + (long)(2 * d) * HWC + l]     = o2[d].x * inv;
      outp[bq + (long)(2 * d + 1) * HWC + l] = o2[d].y * inv;
    }
  }
}

extern "C" void kernel_launch(void* const* d_in, const int* in_sizes, int n_in,
                              void* d_out, int out_size, void* d_ws, size_t ws_size,
                              hipStream_t stream) {
  const float* x        = (const float*)d_in[0];
  const float* ln1_w    = (const float*)d_in[1];
  const float* ln1_b    = (const float*)d_in[2];
  const float* ln2_w    = (const float*)d_in[3];
  const float* ln2_b    = (const float*)d_in[4];
  const float* rq1_w    = (const float*)d_in[5];
  const float* rq1_b    = (const float*)d_in[6];
  const float* rq2_w    = (const float*)d_in[7];
  const float* rq2_b    = (const float*)d_in[8];
  const float* rq3_w    = (const float*)d_in[9];
  const float* rq3_b    = (const float*)d_in[10];
  const float* r_factor = (const float*)d_in[11];
  const float* rfin_w   = (const float*)d_in[12];
  const float* rfin_b   = (const float*)d_in[13];
  const float* cq1_w    = (const float*)d_in[14];
  const float* cq1_b    = (const float*)d_in[15];
  const float* cq2_w    = (const float*)d_in[16];
  const float* cq2_b    = (const float*)d_in[17];
  const float* cq3_w    = (const float*)d_in[18];
  const float* cq3_b    = (const float*)d_in[19];
  const float* c_factor = (const float*)d_in[20];
  const float* cfin_w   = (const float*)d_in[21];
  const float* cfin_b   = (const float*)d_in[22];
  const float* pin_w    = (const float*)d_in[23];
  const float* pin_b    = (const float*)d_in[24];
  const float* dw_w     = (const float*)d_in[25];
  const float* dw_b     = (const float*)d_in[26];
  const float* pout_w   = (const float*)d_in[27];
  const float* pout_b   = (const float*)d_in[28];

  float* ws = (float*)d_ws;
  // Per-batch arena, total 49,055,696 floats (~196 MB). Lifetimes audited (r7).
  float* A    = ws;                     // 14,155,776
  float* S1   = ws + 14155776L;         //  4,718,592
  float* B680 = ws;                     // 25,067,520
  float* Bp   = ws + 25067520L;         // 14,155,776
  float* G    = ws + 25067520L;         // 12,533,760
  float* KV   = ws + 39223296L;         //  9,437,184
  float* S2   = ws + 39223296L;         //  4,718,592 (after KV dead)
  float* S3   = ws + 43941888L;         //  4,718,592 (after KV dead; persists through GDFN)
  float* WT   = ws + 48660480L;
  float* wt_rq1  = WT;                  // 49,152 (LN1-folded)
  float* wt_comb = WT + 49152;          // 49,152 (cq1 . rfin fused)
  float* Kb_comb = WT + 98304;          // 384
  float* wt_cfin = WT + 98688;          // 16,384
  float* wt_pin  = WT + 115072;         // 87,040 (LN2-folded)
  float* wt_pout = WT + 202112;         // 43,520  -> ends WT+245,632
  float* musig_x  = ws + 48906112L;     // 73,728 (18432 float4)
  float* musig_s3 = ws + 48979840L;     // 73,728
  float* S_rq1  = ws + 49053568L;       // 384
  float* Kb_rq1 = ws + 49053952L;       // 384
  float* S_pin  = ws + 49054336L;       // 680
  float* Kb_pin = ws + 49055016L;       // 680  -> total 49,055,696 floats

  // ---- weight prep (once) ----
  prepfold_k<<<dim3(192), 256, 0, stream>>>(rq1_w, ln1_w, wt_rq1, 384, 128);
  prepfold_k<<<dim3(340), 256, 0, stream>>>(pin_w, ln2_w, wt_pin, 680, 128);
  wprod_k<<<dim3(192), 256, 0, stream>>>(cq1_w, rfin_w, rfin_b, cq1_b, wt_comb, Kb_comb, 384, 128, 128);
  wtr_k<<<dim3(64),  256, 0, stream>>>(cfin_w, wt_cfin, 128, 128);
  wtr_k<<<dim3(170), 256, 0, stream>>>(pout_w, wt_pout, 128, 340);
  rowsum_k<<<dim3(2), 256, 0, stream>>>(wt_rq1, rq1_w, ln1_b, rq1_b, S_rq1, Kb_rq1, 384, 128);
  rowsum_k<<<dim3(3), 256, 0, stream>>>(wt_pin, pin_w, ln2_b, pin_b, S_pin, Kb_pin, 680, 128);

  for (int nb = 0; nb < 2; ++nb) {
    const float* x_b = x + (long)nb * 128 * HWC;
    float* out_b = (float*)d_out + (long)nb * 128 * HWC;

    // ---- row attention branch (LN1 folded into rq1 conv) ----
    stat_k<<<72, 256, 0, stream>>>((const f2*)x_b, (float4*)musig_x);
    conv1x1_k<128, 384, 32, false, true><<<dim3(72, 12), 256, 0, stream>>>(
        (const f2*)x_b, wt_rq1, Kb_rq1, nullptr, (f2*)A, (const float4*)musig_x, S_rq1);
    dwdw_k<false, false><<<dim3(36, 384), 256, 0, stream>>>(A, rq2_w, rq2_b, rq3_w, rq3_b, Bp);
    rpk_k<<<768, 384, 0, stream>>>(Bp, KV);
    attn_k<<<768, 384, 0, stream>>>(Bp, KV, S1, r_factor);

    // ---- column branch: (cq1 . rfin) fused conv on row-attn output; transposed 3x3; dwdw writes transposed ----
    conv1x1_k<128, 384, 32, false, false><<<dim3(72, 12), 256, 0, stream>>>(
        (const f2*)S1, wt_comb, Kb_comb, nullptr, (f2*)A, nullptr, nullptr);
    dwdw_k<true, true><<<dim3(36, 384), 256, 0, stream>>>(A, cq2_w, cq2_b, cq3_w, cq3_b, Bp);
    rpk_k<<<768, 384, 0, stream>>>(Bp, KV);
    attn_k<<<768, 384, 0, stream>>>(Bp, KV, S1, c_factor);            // out in (c,w,h)
    thw_k<<<dim3(36, 128), 256, 0, stream>>>(S1, S2);                 // -> (c,h,w)
    conv1x1_k<128, 128, 32, true, false><<<dim3(72, 4), 256, 0, stream>>>(
        (const f2*)S2, wt_cfin, cfin_b, (const f2*)x_b, (f2*)S3, nullptr, nullptr);  // xnew

    // ---- GDFN (LN2 folded into pin conv) ----
    stat_k<<<72, 256, 0, stream>>>((const f2*)S3, (float4*)musig_s3);
    conv1x1_k<128, 680, 40, false, true><<<dim3(72, 17), 256, 0, stream>>>(
        (const f2*)S3, wt_pin, Kb_pin, nullptr, (f2*)B680, (const float4*)musig_s3, S_pin);
    dw3gate_k<<<48960, 256, 0, stream>>>(B680, dw_w, dw_b, G);
    conv1x1_k<340, 128, 32, true, false><<<dim3(72, 4), 256, 0, stream>>>(
        (const f2*)G, wt_pout, pout_b, (const f2*)S3, (f2*)out_b, nullptr, nullptr);
  }
}

// Round 10
// 1773.906 us; speedup vs baseline: 1.4783x; 1.4783x over previous
//
#include <hip/hip_runtime.h>

#define HWC 36864
#define HW2 18432
#define WID 192
#define LOG2E 1.4426950408889634f

typedef float f2 __attribute__((ext_vector_type(2)));

__device__ __forceinline__ float gelu_exact(float v) {
  return 0.5f * v * (1.0f + erff(v * 0.70710678118654752f));
}

// ---- weight transpose: (Cout,Cin) -> (Cin,Cout) ----
__global__ __launch_bounds__(256) void wtr_k(const float* __restrict__ w, float* __restrict__ o,
                                             int Cout, int Cin) {
  int i = blockIdx.x * 256 + threadIdx.x;
  if (i < Cout * Cin) { int co = i / Cin, ci = i - co * Cin; o[ci * Cout + co] = w[i]; }
}

// ---- weight transpose with LN-gamma fold: wt[ci][co] = w[co][ci]*lnw[ci] ----
__global__ __launch_bounds__(256) void prepfold_k(const float* __restrict__ w, const float* __restrict__ lnw,
                                                  float* __restrict__ o, int Cout, int Cin) {
  int i = blockIdx.x * 256 + threadIdx.x;
  if (i < Cout * Cin) { int co = i / Cin, ci = i - co * Cin; o[ci * Cout + co] = w[i] * lnw[ci]; }
}

// ---- per-co reductions for the LN fold ----
__global__ __launch_bounds__(256) void rowsum_k(const float* __restrict__ wt_t, const float* __restrict__ w_orig,
                                                const float* __restrict__ lnb, const float* __restrict__ bias,
                                                float* __restrict__ S, float* __restrict__ Kb,
                                                int Cout, int Cin) {
  int co = blockIdx.x * 256 + threadIdx.x;
  if (co >= Cout) return;
  float s = 0.f, kb = 0.f;
  for (int ci = 0; ci < Cin; ++ci) {
    s += wt_t[ci * Cout + co];
    kb = fmaf(w_orig[co * Cin + ci], lnb[ci], kb);
  }
  S[co] = s;
  Kb[co] = kb + bias[co];
}

// ---- conv-conv fusion: wt[ci][co] = sum_k w2[co][k]*w1[k][ci]; Kb[co] = b2[co] + sum_k w2[co][k]*b1[k] ----
__global__ __launch_bounds__(256) void wprod_k(const float* __restrict__ w2, const float* __restrict__ w1,
                                               const float* __restrict__ b1, const float* __restrict__ b2,
                                               float* __restrict__ wt, float* __restrict__ Kb,
                                               int Cout, int Cmid, int Cin) {
  int i = blockIdx.x * 256 + threadIdx.x;
  if (i >= Cout * Cin) return;
  int co = i / Cin, ci = i - co * Cin;
  float s = 0.f;
  for (int k = 0; k < Cmid; ++k)
    s = fmaf(w2[co * Cmid + k], w1[k * Cin + ci], s);
  wt[ci * Cout + co] = s;
  if (ci == 0) {
    float kb = 0.f;
    for (int k = 0; k < Cmid; ++k) kb = fmaf(w2[co * Cmid + k], b1[k], kb);
    Kb[co] = kb + b2[co];
  }
}

// ---- per-pixel LN stats over C=128 for ONE batch image: musig[p] = {mu0, rs0, mu1, rs1} ----
__global__ __launch_bounds__(256) void stat_k(const f2* __restrict__ x, float4* __restrict__ musig) {
  int p = blockIdx.x * 256 + threadIdx.x;        // 0 .. HW2-1
  f2 s = {0.f, 0.f}, q = {0.f, 0.f};
  for (int c = 0; c < 128; ++c) {
    f2 v = x[p + (long)c * HW2];
    s += v;
    q = __builtin_elementwise_fma(v, v, q);
  }
  f2 mu = s * (1.0f / 128.0f);
  f2 var = q * (1.0f / 128.0f) - mu * mu;
  musig[p] = make_float4(mu.x, rsqrtf(var.x + 1e-5f), mu.y, rsqrtf(var.y + 1e-5f));
}

// ---- conv1x1 as GEMM for ONE batch image, f2-packed (2 pixels/thread) ----
template<int CIN, int COUT, int TILE, bool RESID, bool FOLD>
__global__ __launch_bounds__(256) void conv1x1_k(const f2* __restrict__ in, const float* __restrict__ wt,
                                                 const float* __restrict__ bias, const f2* __restrict__ resid,
                                                 f2* __restrict__ out,
                                                 const float4* __restrict__ musig, const float* __restrict__ S) {
  int p = blockIdx.x * 256 + threadIdx.x;    // 0 .. HW2-1
  int co0 = blockIdx.y * TILE;
  const f2* ip = in + p;
  const float* wp = wt + co0;
  f2 acc[TILE];
  #pragma unroll
  for (int i = 0; i < TILE; ++i) acc[i] = (f2){0.f, 0.f};
  for (int ci = 0; ci < CIN; ++ci) {
    f2 v = ip[(long)ci * HW2];
    #pragma unroll
    for (int co = 0; co < TILE; ++co) {
      float w = wp[ci * COUT + co];
      acc[co] = __builtin_elementwise_fma(v, (f2){w, w}, acc[co]);
    }
  }
  float4 ms;
  if (FOLD) ms = musig[p];
  #pragma unroll
  for (int co = 0; co < TILE; ++co) {
    f2 r;
    if (FOLD) {
      float sc = S[co0 + co], kb = bias[co0 + co];
      r.x = fmaf(ms.y, acc[co].x - ms.x * sc, kb);
      r.y = fmaf(ms.w, acc[co].y - ms.z * sc, kb);
    } else {
      float bc = bias[co0 + co];
      r = acc[co] + (f2){bc, bc};
    }
    if (RESID) r += resid[(long)(co0 + co) * HW2 + p];
    out[(long)(co0 + co) * HW2 + p] = r;
  }
}

// ---- fused depthwise 3x3 -> depthwise 3x3 for ONE batch image (zero-pad exact) ----
template<bool TR, bool TROUT>
__global__ __launch_bounds__(256) void dwdw_k(const float* __restrict__ in,
                                              const float* __restrict__ w2, const float* __restrict__ b2,
                                              const float* __restrict__ w3, const float* __restrict__ b3,
                                              float* __restrict__ out) {
  __shared__ float sIn[36 * 36];
  __shared__ float sMid[34 * 34];
  __shared__ float sOut[32 * 33];
  int tid = threadIdx.x;
  int tb = blockIdx.x;                 // 0..35 (6x6 tiles of 32x32)
  int c = blockIdx.y;                  // channel/plane
  int h0 = (tb / 6) * 32, w0 = (tb % 6) * 32;
  const float* ip = in + (long)c * HWC;
  float k2[9], k3[9];
  #pragma unroll
  for (int i = 0; i < 3; ++i)
    #pragma unroll
    for (int j = 0; j < 3; ++j) {
      k2[i * 3 + j] = w2[c * 9 + (TR ? j * 3 + i : i * 3 + j)];
      k3[i * 3 + j] = w3[c * 9 + (TR ? j * 3 + i : i * 3 + j)];
    }
  float bb2 = b2[c], bb3 = b3[c];
  for (int t = tid; t < 36 * 36; t += 256) {
    int i = t / 36, j = t - i * 36;
    int h = h0 - 2 + i, w = w0 - 2 + j;
    sIn[t] = (h >= 0 && h < WID && w >= 0 && w < WID) ? ip[h * WID + w] : 0.f;
  }
  __syncthreads();
  for (int t = tid; t < 34 * 34; t += 256) {
    int i = t / 34, j = t - i * 34;
    int h = h0 - 1 + i, w = w0 - 1 + j;
    float acc = 0.f;
    if (h >= 0 && h < WID && w >= 0 && w < WID) {
      acc = bb2;
      #pragma unroll
      for (int di = 0; di < 3; ++di)
        #pragma unroll
        for (int dj = 0; dj < 3; ++dj)
          acc = fmaf(k2[di * 3 + dj], sIn[(i + di) * 36 + j + dj], acc);
    }
    sMid[t] = acc;
  }
  __syncthreads();
  #pragma unroll
  for (int tt = 0; tt < 4; ++tt) {
    int t = tid + tt * 256;
    int i = t >> 5, j = t & 31;
    float acc = bb3;
    #pragma unroll
    for (int di = 0; di < 3; ++di)
      #pragma unroll
      for (int dj = 0; dj < 3; ++dj)
        acc = fmaf(k3[di * 3 + dj], sMid[(i + di) * 34 + j + dj], acc);
    if (TROUT) sOut[i * 33 + j] = acc;
    else       out[(long)c * HWC + (h0 + i) * WID + w0 + j] = acc;
  }
  if (TROUT) {
    __syncthreads();
    #pragma unroll
    for (int tt = 0; tt < 4; ++tt) {
      int t = tid + tt * 256;
      int a = t >> 5, b = t & 31;
      out[(long)c * HWC + (w0 + a) * WID + h0 + b] = sOut[b * 33 + a];
    }
  }
}

// ---- fused depthwise 3x3 (680ch) + cross-GELU gate -> 340ch, ONE batch image ----
__global__ __launch_bounds__(256) void dw3gate_k(const float* __restrict__ in, const float* __restrict__ wk,
                                                 const float* __restrict__ bias, float* __restrict__ g) {
  int idx = blockIdx.x * 256 + threadIdx.x;      // < 340*HWC
  int w = idx % WID;
  int t = idx / WID;
  int h = t % WID;
  int c = t / WID;            // 0..339
  const float* ip1 = in + (long)c * HWC;
  const float* ip2 = ip1 + (long)340 * HWC;
  float a = bias[c], bb = bias[c + 340];
  #pragma unroll
  for (int i = 0; i < 3; ++i) {
    int hh = h + i - 1;
    if (hh < 0 || hh >= WID) continue;
    #pragma unroll
    for (int j = 0; j < 3; ++j) {
      int ww = w + j - 1;
      if (ww < 0 || ww >= WID) continue;
      int off = hh * WID + ww;
      a  = fmaf(wk[c * 9 + i * 3 + j],         ip1[off], a);
      bb = fmaf(wk[(c + 340) * 9 + i * 3 + j], ip2[off], bb);
    }
  }
  g[(long)c * HWC + h * WID + w] = gelu_exact(bb) * a + gelu_exact(a) * bb;
}

// ---- h<->w transpose of one (192,192) plane per blockIdx.y ----
__global__ __launch_bounds__(256) void thw_k(const float* __restrict__ in, float* __restrict__ out) {
  __shared__ float tile[32][33];
  int tb = blockIdx.x;         // 0..35
  int h0 = (tb / 6) * 32, w0 = (tb % 6) * 32;
  long base = (long)blockIdx.y * HWC;
  int tx = threadIdx.x & 31, ty = threadIdx.x >> 5;
  #pragma unroll
  for (int k = 0; k < 4; ++k)
    tile[ty + 8 * k][tx] = in[base + (h0 + ty + 8 * k) * WID + w0 + tx];
  __syncthreads();
  #pragma unroll
  for (int k = 0; k < 4; ++k)
    out[base + (w0 + ty + 8 * k) * WID + h0 + tx] = tile[tx][ty + 8 * k];
}

// ---- repack K,V rows of one batch's qkv into kv[g*192+r][j][64] (K d=0..31, V d=32..63) ----
__global__ __launch_bounds__(384) void rpk_k(const float* __restrict__ qkv, float* __restrict__ kv) {
  __shared__ float T[64 * 193];
  int bid = blockIdx.x;            // g*192 + r
  int r = bid % WID;
  int g = bid / WID;               // 0..3
  int t = threadIdx.x;
  for (int e = t; e < 64 * 192; e += 384) {
    int ch = e / 192, j = e - ch * 192;      // coalesced read along j
    int which = ch >> 5, d = ch & 31;
    long plane = 128 + which * 128 + g * 32 + d;
    T[ch * 193 + j] = qkv[plane * HWC + (long)r * WID + j];
  }
  __syncthreads();
  long ob = (long)bid * (192 * 64);
  for (int e = t; e < 64 * 192; e += 384) {
    int j = e >> 6, c = e & 63;              // coalesced write
    kv[ob + e] = T[c * 193 + j];
  }
}

// ---- axial attention (one batch image): one block (192 thr) per (g, row) ----
// K/V staged once per block into LDS (coalesced float4 copy of rpk's [j][64] layout:
// row j at byte 256j -> 16B-aligned b128 reads; linear writes conflict-free; 48KB ->
// 3 blocks/CU). Inner loop reads are same-address BROADCASTS (conflict-free, no global
// latency) -- r7/r8/r9 post-mortems proved any wave-uniform global-load loop is a serial
// latency chain (165/211/307 us); this bounds the loop by LDS issue + VALU instead.
__global__ __launch_bounds__(192) void attn_k(const float* __restrict__ qkv,
                                              const float* __restrict__ kv,
                                              float* __restrict__ outp,
                                              const float* __restrict__ factor) {
  __shared__ float KVs[192 * 64];
  int l = threadIdx.x;
  int bid = blockIdx.x;
  int r = bid % WID;
  int g = bid / WID;
  long bq = (long)(g * 32) * HWC + (long)r * WID;
  // stage K/V: 12288 floats = 3072 float4, 16 per thread, fully coalesced
  {
    const float4* src = (const float4*)(kv + (long)bid * (192 * 64));
    float4* dst = (float4*)KVs;
    #pragma unroll
    for (int k = 0; k < 16; ++k)
      dst[l + k * 192] = src[l + k * 192];
  }
  // Q -> registers, l2-normalize
  f2 qr2[16]; float qn = 0.f;
  #pragma unroll
  for (int d = 0; d < 16; ++d) {
    f2 a = { qkv[bq + (long)(2 * d) * HWC + l], qkv[bq + (long)(2 * d + 1) * HWC + l] };
    qr2[d] = a;
    qn += a.x * a.x + a.y * a.y;
  }
  float qs = 1.0f / fmaxf(sqrtf(qn), 1e-12f);
  #pragma unroll
  for (int d = 0; d < 16; ++d) qr2[d] *= qs;
  __syncthreads();

  float f = factor[0];
  float fl2 = f * LOG2E, ml2 = fabsf(f) * LOG2E;   // |q.k|<=1 -> exact shift, no max pass
  f2 o2[16];
  #pragma unroll
  for (int d = 0; d < 16; ++d) o2[d] = (f2){0.f, 0.f};
  float lsum = 0.f;
  #pragma unroll 2
  for (int j = 0; j < WID; ++j) {
    const float4* kj = (const float4*)(KVs + j * 64);   // broadcast reads
    float4 k0 = kj[0], k1 = kj[1], k2 = kj[2], k3 = kj[3];
    float4 k4 = kj[4], k5 = kj[5], k6 = kj[6], k7 = kj[7];
    f2 a0 = {0.f, 0.f}, a1 = {0.f, 0.f}, a2 = {0.f, 0.f}, a3 = {0.f, 0.f};
    a0 = __builtin_elementwise_fma(qr2[0],  (f2){k0.x, k0.y}, a0);
    a1 = __builtin_elementwise_fma(qr2[1],  (f2){k0.z, k0.w}, a1);
    a2 = __builtin_elementwise_fma(qr2[2],  (f2){k1.x, k1.y}, a2);
    a3 = __builtin_elementwise_fma(qr2[3],  (f2){k1.z, k1.w}, a3);
    a0 = __builtin_elementwise_fma(qr2[4],  (f2){k2.x, k2.y}, a0);
    a1 = __builtin_elementwise_fma(qr2[5],  (f2){k2.z, k2.w}, a1);
    a2 = __builtin_elementwise_fma(qr2[6],  (f2){k3.x, k3.y}, a2);
    a3 = __builtin_elementwise_fma(qr2[7],  (f2){k3.z, k3.w}, a3);
    a0 = __builtin_elementwise_fma(qr2[8],  (f2){k4.x, k4.y}, a0);
    a1 = __builtin_elementwise_fma(qr2[9],  (f2){k4.z, k4.w}, a1);
    a2 = __builtin_elementwise_fma(qr2[10], (f2){k5.x, k5.y}, a2);
    a3 = __builtin_elementwise_fma(qr2[11], (f2){k5.z, k5.w}, a3);
    a0 = __builtin_elementwise_fma(qr2[12], (f2){k6.x, k6.y}, a0);
    a1 = __builtin_elementwise_fma(qr2[13], (f2){k6.z, k6.w}, a1);
    a2 = __builtin_elementwise_fma(qr2[14], (f2){k7.x, k7.y}, a2);
    a3 = __builtin_elementwise_fma(qr2[15], (f2){k7.z, k7.w}, a3);
    f2 asum = (a0 + a1) + (a2 + a3);
    float p = exp2f(fmaf(asum.x + asum.y, fl2, -ml2));
    lsum += p;
    f2 ps = {p, p};
    float4 v0 = kj[8],  v1 = kj[9],  v2 = kj[10], v3 = kj[11];
    float4 v4 = kj[12], v5 = kj[13], v6 = kj[14], v7 = kj[15];
    o2[0]  = __builtin_elementwise_fma(ps, (f2){v0.x, v0.y}, o2[0]);
    o2[1]  = __builtin_elementwise_fma(ps, (f2){v0.z, v0.w}, o2[1]);
    o2[2]  = __builtin_elementwise_fma(ps, (f2){v1.x, v1.y}, o2[2]);
    o2[3]  = __builtin_elementwise_fma(ps, (f2){v1.z, v1.w}, o2[3]);
    o2[4]  = __builtin_elementwise_fma(ps, (f2){v2.x, v2.y}, o2[4]);
    o2[5]  = __builtin_elementwise_fma(ps, (f2){v2.z, v2.w}, o2[5]);
    o2[6]  = __builtin_elementwise_fma(ps, (f2){v3.x, v3.y}, o2[6]);
    o2[7]  = __builtin_elementwise_fma(ps, (f2){v3.z, v3.w}, o2[7]);
    o2[8]  = __builtin_elementwise_fma(ps, (f2){v4.x, v4.y}, o2[8]);
    o2[9]  = __builtin_elementwise_fma(ps, (f2){v4.z, v4.w}, o2[9]);
    o2[10] = __builtin_elementwise_fma(ps, (f2){v5.x, v5.y}, o2[10]);
    o2[11] = __builtin_elementwise_fma(ps, (f2){v5.z, v5.w}, o2[11]);
    o2[12] = __builtin_elementwise_fma(ps, (f2){v6.x, v6.y}, o2[12]);
    o2[13] = __builtin_elementwise_fma(ps, (f2){v6.z, v6.w}, o2[13]);
    o2[14] = __builtin_elementwise_fma(ps, (f2){v7.x, v7.y}, o2[14]);
    o2[15] = __builtin_elementwise_fma(ps, (f2){v7.z, v7.w}, o2[15]);
  }
  float inv = 1.0f / lsum;
  #pragma unroll
  for (int d = 0; d < 16; ++d) {
    outp[bq + (long)(2 * d) * HWC + l]     = o2[d].x * inv;
    outp[bq + (long)(2 * d + 1) * HWC + l] = o2[d].y * inv;
  }
}

extern "C" void kernel_launch(void* const* d_in, const int* in_sizes, int n_in,
                              void* d_out, int out_size, void* d_ws, size_t ws_size,
                              hipStream_t stream) {
  const float* x        = (const float*)d_in[0];
  const float* ln1_w    = (const float*)d_in[1];
  const float* ln1_b    = (const float*)d_in[2];
  const float* ln2_w    = (const float*)d_in[3];
  const float* ln2_b    = (const float*)d_in[4];
  const float* rq1_w    = (const float*)d_in[5];
  const float* rq1_b    = (const float*)d_in[6];
  const float* rq2_w    = (const float*)d_in[7];
  const float* rq2_b    = (const float*)d_in[8];
  const float* rq3_w    = (const float*)d_in[9];
  const float* rq3_b    = (const float*)d_in[10];
  const float* r_factor = (const float*)d_in[11];
  const float* rfin_w   = (const float*)d_in[12];
  const float* rfin_b   = (const float*)d_in[13];
  const float* cq1_w    = (const float*)d_in[14];
  const float* cq1_b    = (const float*)d_in[15];
  const float* cq2_w    = (const float*)d_in[16];
  const float* cq2_b    = (const float*)d_in[17];
  const float* cq3_w    = (const float*)d_in[18];
  const float* cq3_b    = (const float*)d_in[19];
  const float* c_factor = (const float*)d_in[20];
  const float* cfin_w   = (const float*)d_in[21];
  const float* cfin_b   = (const float*)d_in[22];
  const float* pin_w    = (const float*)d_in[23];
  const float* pin_b    = (const float*)d_in[24];
  const float* dw_w     = (const float*)d_in[25];
  const float* dw_b     = (const float*)d_in[26];
  const float* pout_w   = (const float*)d_in[27];
  const float* pout_b   = (const float*)d_in[28];

  float* ws = (float*)d_ws;
  // Per-batch arena, total 49,055,696 floats (~196 MB). Lifetimes audited (r7).
  float* A    = ws;                     // 14,155,776
  float* S1   = ws + 14155776L;         //  4,718,592
  float* B680 = ws;                     // 25,067,520
  float* Bp   = ws + 25067520L;         // 14,155,776
  float* G    = ws + 25067520L;         // 12,533,760
  float* KV   = ws + 39223296L;         //  9,437,184
  float* S2   = ws + 39223296L;         //  4,718,592 (after KV dead)
  float* S3   = ws + 43941888L;         //  4,718,592 (after KV dead; persists through GDFN)
  float* WT   = ws + 48660480L;
  float* wt_rq1  = WT;                  // 49,152 (LN1-folded)
  float* wt_comb = WT + 49152;          // 49,152 (cq1 . rfin fused)
  float* Kb_comb = WT + 98304;          // 384
  float* wt_cfin = WT + 98688;          // 16,384
  float* wt_pin  = WT + 115072;         // 87,040 (LN2-folded)
  float* wt_pout = WT + 202112;         // 43,520  -> ends WT+245,632
  float* musig_x  = ws + 48906112L;     // 73,728 (18432 float4)
  float* musig_s3 = ws + 48979840L;     // 73,728
  float* S_rq1  = ws + 49053568L;       // 384
  float* Kb_rq1 = ws + 49053952L;       // 384
  float* S_pin  = ws + 49054336L;       // 680
  float* Kb_pin = ws + 49055016L;       // 680  -> total 49,055,696 floats

  // ---- weight prep (once) ----
  prepfold_k<<<dim3(192), 256, 0, stream>>>(rq1_w, ln1_w, wt_rq1, 384, 128);
  prepfold_k<<<dim3(340), 256, 0, stream>>>(pin_w, ln2_w, wt_pin, 680, 128);
  wprod_k<<<dim3(192), 256, 0, stream>>>(cq1_w, rfin_w, rfin_b, cq1_b, wt_comb, Kb_comb, 384, 128, 128);
  wtr_k<<<dim3(64),  256, 0, stream>>>(cfin_w, wt_cfin, 128, 128);
  wtr_k<<<dim3(170), 256, 0, stream>>>(pout_w, wt_pout, 128, 340);
  rowsum_k<<<dim3(2), 256, 0, stream>>>(wt_rq1, rq1_w, ln1_b, rq1_b, S_rq1, Kb_rq1, 384, 128);
  rowsum_k<<<dim3(3), 256, 0, stream>>>(wt_pin, pin_w, ln2_b, pin_b, S_pin, Kb_pin, 680, 128);

  for (int nb = 0; nb < 2; ++nb) {
    const float* x_b = x + (long)nb * 128 * HWC;
    float* out_b = (float*)d_out + (long)nb * 128 * HWC;

    // ---- row attention branch (LN1 folded into rq1 conv) ----
    stat_k<<<72, 256, 0, stream>>>((const f2*)x_b, (float4*)musig_x);
    conv1x1_k<128, 384, 32, false, true><<<dim3(72, 12), 256, 0, stream>>>(
        (const f2*)x_b, wt_rq1, Kb_rq1, nullptr, (f2*)A, (const float4*)musig_x, S_rq1);
    dwdw_k<false, false><<<dim3(36, 384), 256, 0, stream>>>(A, rq2_w, rq2_b, rq3_w, rq3_b, Bp);
    rpk_k<<<768, 384, 0, stream>>>(Bp, KV);
    attn_k<<<768, 192, 0, stream>>>(Bp, KV, S1, r_factor);

    // ---- column branch: (cq1 . rfin) fused conv on row-attn output; transposed 3x3; dwdw writes transposed ----
    conv1x1_k<128, 384, 32, false, false><<<dim3(72, 12), 256, 0, stream>>>(
        (const f2*)S1, wt_comb, Kb_comb, nullptr, (f2*)A, nullptr, nullptr);
    dwdw_k<true, true><<<dim3(36, 384), 256, 0, stream>>>(A, cq2_w, cq2_b, cq3_w, cq3_b, Bp);
    rpk_k<<<768, 384, 0, stream>>>(Bp, KV);
    attn_k<<<768, 192, 0, stream>>>(Bp, KV, S1, c_factor);            // out in (c,w,h)
    thw_k<<<dim3(36, 128), 256, 0, stream>>>(S1, S2);                 // -> (c,h,w)
    conv1x1_k<128, 128, 32, true, false><<<dim3(72, 4), 256, 0, stream>>>(
        (const f2*)S2, wt_cfin, cfin_b, (const f2*)x_b, (f2*)S3, nullptr, nullptr);  // xnew

    // ---- GDFN (LN2 folded into pin conv) ----
    stat_k<<<72, 256, 0, stream>>>((const f2*)S3, (float4*)musig_s3);
    conv1x1_k<128, 680, 40, false, true><<<dim3(72, 17), 256, 0, stream>>>(
        (const f2*)S3, wt_pin, Kb_pin, nullptr, (f2*)B680, (const float4*)musig_s3, S_pin);
    dw3gate_k<<<48960, 256, 0, stream>>>(B680, dw_w, dw_b, G);
    conv1x1_k<340, 128, 32, true, false><<<dim3(72, 4), 256, 0, stream>>>(
        (const f2*)G, wt_pout, pout_b, (const f2*)S3, (f2*)out_b, nullptr, nullptr);
  }
}